// Round 6
// baseline (1626.094 us; speedup 1.0000x reference)
//
#include <hip/hip_runtime.h>
#include <math.h>

#define CDIM 768

typedef __attribute__((ext_vector_type(8))) _Float16 h8;
typedef __attribute__((ext_vector_type(4))) float f4;

template <int SRC> struct EltT;                    // source element type
template <> struct EltT<0> { using t = float; };   // fp32, cvt on the fly
template <> struct EltT<1> { using t = _Float16; };// fp16 direct

// ---------------- reductions (256-thread blocks, 4 waves) ----------------
__device__ __forceinline__ float block_reduce_sum(float v, float* sm) {
#pragma unroll
  for (int o = 32; o > 0; o >>= 1) v += __shfl_down(v, o, 64);
  const int lane = threadIdx.x & 63, wid = threadIdx.x >> 6;
  __syncthreads();  // protect prior use of sm
  if (lane == 0) sm[wid] = v;
  __syncthreads();
  return sm[0] + sm[1] + sm[2] + sm[3];
}

__device__ __forceinline__ float block_reduce_max(float v, float* sm) {
#pragma unroll
  for (int o = 32; o > 0; o >>= 1) v = fmaxf(v, __shfl_down(v, o, 64));
  const int lane = threadIdx.x & 63, wid = threadIdx.x >> 6;
  __syncthreads();
  if (lane == 0) sm[wid] = v;
  __syncthreads();
  return fmaxf(fmaxf(sm[0], sm[1]), fmaxf(sm[2], sm[3]));
}

__device__ __forceinline__ float softplusf(float x) {
  return (x > 0.f) ? x + log1pf(expf(-x)) : log1pf(expf(x));
}

__device__ __forceinline__ h8 cvt8(const float4 u, const float4 v) {
  h8 r;
  r[0] = (_Float16)u.x; r[1] = (_Float16)u.y;
  r[2] = (_Float16)u.z; r[3] = (_Float16)u.w;
  r[4] = (_Float16)v.x; r[5] = (_Float16)v.y;
  r[6] = (_Float16)v.z; r[7] = (_Float16)v.w;
  return r;
}

// ================= fp16 MFMA NT GEMM, 128x128 tile, BK=32 =================
// C[m,n] = sum_k A[m,k]*B[n,k]  (A:[M,K], B:[N,K] row-major).
// 256 thr = 4 waves (2x2), per-wave 64x64 via 4x4 frags of 16x16x32 MFMA.
// SRC 0: A/B are fp32, converted to fp16 during LDS staging (no pre-split
//        copies). SRC 1: A/B already fp16.
// A/B frags: 8 contiguous k per lane (same convention both operands -> any
// internal k-permutation cancels). C/D: col=lane&15, row=(lane>>4)*4+reg
// (m89/m91-verified).  LDS pitch 40 halves (80 B, 16B-aligned rows).
// EPI: 1 = Q epilogue: e_q=fp16(acc+bias), e_q2=fp16((acc+bias)^2)
//      2 = O1 = acc
//      3 = combine: O1 = O1*INV_SCALE - 2.35*sqrt(max(acc,0)/CDIM) (in-place)
//      5 = O1 = g*(acc+bias) + (1-g)*resid, g=sigmoid(gate[0])
//      6 = proj_kv: col<768 -> O1[row*768+col]=acc+bias
//                   col>=768 -> O2[row*768+col-768]=softplus(acc+bias)+1e-6
template <int SRC, int EPI>
__global__ __launch_bounds__(256) void hgemm_nt(
    const void* __restrict__ Av, const void* __restrict__ Bv,
    const float* __restrict__ bias, float* __restrict__ O1,
    float* __restrict__ O2, int M, int N, int K, long sA, long sB, long sC,
    _Float16* __restrict__ e_q, _Float16* __restrict__ e_q2,
    const float* __restrict__ resid, const float* __restrict__ gate) {
  using AT = typename EltT<SRC>::t;
  __shared__ _Float16 As[128][40], Bs[128][40];
  const int t = threadIdx.x;
  const int z = blockIdx.z;
  const AT* pA = (const AT*)Av + (size_t)z * sA;
  const AT* pB = (const AT*)Bv + (size_t)z * sB;
  float* pC = O1 + (size_t)z * sC;
  const int bm = blockIdx.y * 128, bn = blockIdx.x * 128;
  const int lane = t & 63, w = t >> 6;
  const int wr = w >> 1, wc = w & 1;
  const int lr = lane & 15, kb = (lane >> 4) * 8;
  // staging: 512 chunks of 8 elements per 128x32 tile; thread owns t, t+256
  const int r0 = t >> 2, kc0 = (t & 3) * 8;
  const int r1 = (t + 256) >> 2, kc1 = ((t + 256) & 3) * 8;
  const AT* gA0 = pA + (size_t)(bm + r0) * K + kc0;
  const AT* gA1 = pA + (size_t)(bm + r1) * K + kc1;
  const AT* gB0 = pB + (size_t)(bn + r0) * K + kc0;
  const AT* gB1 = pB + (size_t)(bn + r1) * K + kc1;
  f4 acc[4][4];
#pragma unroll
  for (int i = 0; i < 4; ++i)
#pragma unroll
    for (int j = 0; j < 4; ++j) acc[i][j] = (f4){0.f, 0.f, 0.f, 0.f};
  // prefetch registers (per-SRC set; unused set is dead code)
  float4 fA0u, fA0v, fA1u, fA1v, fB0u, fB0v, fB1u, fB1v;
  h8 hA0, hA1, hB0, hB1;
  // prologue: stage tile 0
  if constexpr (SRC == 0) {
    fA0u = *(const float4*)(gA0); fA0v = *(const float4*)(gA0 + 4);
    fA1u = *(const float4*)(gA1); fA1v = *(const float4*)(gA1 + 4);
    fB0u = *(const float4*)(gB0); fB0v = *(const float4*)(gB0 + 4);
    fB1u = *(const float4*)(gB1); fB1v = *(const float4*)(gB1 + 4);
  } else {
    hA0 = *(const h8*)(gA0); hA1 = *(const h8*)(gA1);
    hB0 = *(const h8*)(gB0); hB1 = *(const h8*)(gB1);
  }
  for (int kk = 0; kk < K; kk += 32) {
    __syncthreads();  // prior compute done before LDS overwrite
    if constexpr (SRC == 0) {
      *(h8*)&As[r0][kc0] = cvt8(fA0u, fA0v);
      *(h8*)&As[r1][kc1] = cvt8(fA1u, fA1v);
      *(h8*)&Bs[r0][kc0] = cvt8(fB0u, fB0v);
      *(h8*)&Bs[r1][kc1] = cvt8(fB1u, fB1v);
    } else {
      *(h8*)&As[r0][kc0] = hA0; *(h8*)&As[r1][kc1] = hA1;
      *(h8*)&Bs[r0][kc0] = hB0; *(h8*)&Bs[r1][kc1] = hB1;
    }
    __syncthreads();
    if (kk + 32 < K) {  // issue next-tile loads; latency hides under MFMAs
      const int o = kk + 32;
      if constexpr (SRC == 0) {
        fA0u = *(const float4*)(gA0 + o); fA0v = *(const float4*)(gA0 + o + 4);
        fA1u = *(const float4*)(gA1 + o); fA1v = *(const float4*)(gA1 + o + 4);
        fB0u = *(const float4*)(gB0 + o); fB0v = *(const float4*)(gB0 + o + 4);
        fB1u = *(const float4*)(gB1 + o); fB1v = *(const float4*)(gB1 + o + 4);
      } else {
        hA0 = *(const h8*)(gA0 + o); hA1 = *(const h8*)(gA1 + o);
        hB0 = *(const h8*)(gB0 + o); hB1 = *(const h8*)(gB1 + o);
      }
    }
    h8 fa[4], fb[4];
#pragma unroll
    for (int i = 0; i < 4; ++i)
      fa[i] = *(const h8*)&As[wr * 64 + i * 16 + lr][kb];
#pragma unroll
    for (int j = 0; j < 4; ++j)
      fb[j] = *(const h8*)&Bs[wc * 64 + j * 16 + lr][kb];
#pragma unroll
    for (int i = 0; i < 4; ++i)
#pragma unroll
      for (int j = 0; j < 4; ++j)
        acc[i][j] = __builtin_amdgcn_mfma_f32_16x16x32_f16(fa[i], fb[j],
                                                           acc[i][j], 0, 0, 0);
  }
  // epilogue
  float g_ = 0.f, og_ = 0.f;
  if constexpr (EPI == 5) {
    g_ = 1.f / (1.f + expf(-gate[0]));
    og_ = 1.f - g_;
  }
  const float INV_SCALE = 0.03608439182435161f;  // 1/sqrt(768)
  const float INV_C = 1.0f / 768.0f;
#pragma unroll
  for (int i = 0; i < 4; ++i)
#pragma unroll
    for (int j = 0; j < 4; ++j) {
      const int colg = bn + wc * 64 + j * 16 + lr;
      float bcol = 0.f;
      if constexpr (EPI == 1 || EPI == 5 || EPI == 6) bcol = bias[colg];
#pragma unroll
      for (int r = 0; r < 4; ++r) {
        const int rowg = bm + wr * 64 + i * 16 + (lane >> 4) * 4 + r;
        const float v = acc[i][j][r];
        if constexpr (EPI == 1) {
          const size_t idx = (size_t)rowg * N + colg;
          const float tq = v + bcol;
          e_q[idx] = (_Float16)tq;
          e_q2[idx] = (_Float16)(tq * tq);
        } else if constexpr (EPI == 2) {
          pC[(size_t)rowg * N + colg] = v;
        } else if constexpr (EPI == 3) {
          const size_t idx = (size_t)rowg * N + colg;
          const float s1 = pC[idx];
          pC[idx] = s1 * INV_SCALE - 2.35f * sqrtf(fmaxf(v, 0.f) * INV_C);
        } else if constexpr (EPI == 5) {
          const size_t idx = (size_t)rowg * N + colg;
          pC[idx] = g_ * (v + bcol) + og_ * resid[idx];
        } else if constexpr (EPI == 6) {
          if (colg < 768)
            O1[(size_t)rowg * 768 + colg] = v + bcol;
          else
            O2[(size_t)rowg * 768 + (colg - 768)] = softplusf(v + bcol) + 1e-6f;
        }
      }
    }
}

// ---- K post: kmuF = fp16(LN(muRaw)); kvarF = fp16(varF) ----
__global__ __launch_bounds__(256) void ln_post_k(
    const float* __restrict__ muRaw, const float* __restrict__ varF,
    const float* __restrict__ lng, const float* __restrict__ lnb,
    _Float16* __restrict__ kmuF, _Float16* __restrict__ kvarF) {
  __shared__ float sm[4];
  const size_t r = blockIdx.x;
  const float* mu = muRaw + r * 768;
  const float* vf = varF + r * 768;
  const int t = threadIdx.x;
  const float x0 = mu[t], x1 = mu[t + 256], x2 = mu[t + 512];
  const float mean = block_reduce_sum(x0 + x1 + x2, sm) * (1.0f / 768.0f);
  const float d0 = x0 - mean, d1 = x1 - mean, d2 = x2 - mean;
  const float var =
      block_reduce_sum(d0 * d0 + d1 * d1 + d2 * d2, sm) * (1.0f / 768.0f);
  const float inv = rsqrtf(var + 1e-5f);
  const float y[3] = {d0 * inv * lng[t] + lnb[t],
                      d1 * inv * lng[t + 256] + lnb[t + 256],
                      d2 * inv * lng[t + 512] + lnb[t + 512]};
  const float sp[3] = {vf[t], vf[t + 256], vf[t + 512]};
#pragma unroll
  for (int c = 0; c < 3; ++c) {
    const size_t idx = r * 768 + t + c * 256;
    kmuF[idx] = (_Float16)y[c];
    kvarF[idx] = (_Float16)sp[c];
  }
}

// ---- V post: Vs = LN(muRaw) + sqrt(varF)*eps, fp32, in-place over muRaw ----
__global__ __launch_bounds__(256) void ln_post_v(
    float* __restrict__ muRaw, const float* __restrict__ varF,
    const float* __restrict__ lng, const float* __restrict__ lnb,
    const float* __restrict__ eps) {
  __shared__ float sm[4];
  const size_t r = blockIdx.x;
  float* mu = muRaw + r * 768;
  const float* vf = varF + r * 768;
  const int t = threadIdx.x;
  const float x0 = mu[t], x1 = mu[t + 256], x2 = mu[t + 512];
  const float mean = block_reduce_sum(x0 + x1 + x2, sm) * (1.0f / 768.0f);
  const float d0 = x0 - mean, d1 = x1 - mean, d2 = x2 - mean;
  const float var =
      block_reduce_sum(d0 * d0 + d1 * d1 + d2 * d2, sm) * (1.0f / 768.0f);
  const float inv = rsqrtf(var + 1e-5f);
  const float y0 = d0 * inv * lng[t] + lnb[t];
  const float y1 = d1 * inv * lng[t + 256] + lnb[t + 256];
  const float y2 = d2 * inv * lng[t + 512] + lnb[t + 512];
  const float* er = eps + r * 768;
  // reads of mu complete before the barrier inside the reductions above
  mu[t]       = y0 + sqrtf(vf[t]) * er[t];
  mu[t + 256] = y1 + sqrtf(vf[t + 256]) * er[t + 256];
  mu[t + 512] = y2 + sqrtf(vf[t + 512]) * er[t + 512];
}

// ---------------- row softmax over 2048, in place ----------------
__global__ __launch_bounds__(256) void softmax_rows(float* __restrict__ S) {
  __shared__ float sm[4];
  float* row = S + (size_t)blockIdx.x * 2048;
  const int t = threadIdx.x;
  float4 v0 = *(float4*)(row + (t << 2));
  float4 v1 = *(float4*)(row + 1024 + (t << 2));
  float mx = fmaxf(fmaxf(fmaxf(v0.x, v0.y), fmaxf(v0.z, v0.w)),
                   fmaxf(fmaxf(v1.x, v1.y), fmaxf(v1.z, v1.w)));
  mx = block_reduce_max(mx, sm);
  v0.x = expf(v0.x - mx); v0.y = expf(v0.y - mx);
  v0.z = expf(v0.z - mx); v0.w = expf(v0.w - mx);
  v1.x = expf(v1.x - mx); v1.y = expf(v1.y - mx);
  v1.z = expf(v1.z - mx); v1.w = expf(v1.w - mx);
  float s = v0.x + v0.y + v0.z + v0.w + v1.x + v1.y + v1.z + v1.w;
  s = block_reduce_sum(s, sm);
  const float r = 1.0f / s;
  v0.x *= r; v0.y *= r; v0.z *= r; v0.w *= r;
  v1.x *= r; v1.y *= r; v1.z *= r; v1.w *= r;
  *(float4*)(row + (t << 2)) = v0;
  *(float4*)(row + 1024 + (t << 2)) = v1;
}

// --- attn @ V_sample: fp32 batched NN GEMM, 128x128, reg-prefetch dbuf ---
__global__ __launch_bounds__(256) void gemm_nn_av(const float* __restrict__ S,
                                                  const float* __restrict__ V,
                                                  float* __restrict__ O) {
  __shared__ float As[16][132], Bs[16][132];
  const int b = blockIdx.z;
  const float* Sb = S + (size_t)b * 1024 * 2048;
  const float* Vb = V + (size_t)b * 2048 * CDIM;
  float* Ob = O + (size_t)b * 1024 * CDIM;
  const int t = threadIdx.x, tx = t & 15, ty = t >> 4;
  const int bm = blockIdx.y * 128, bc = blockIdx.x * 128;
  const int lr = t >> 2, lc = (t & 3) << 2;   // A loader (transpose to LDS)
  const int vr = t >> 5, vc = (t & 31) << 2;  // B loader (direct, 8+8 rows)
  const float* Sp0 = Sb + (size_t)(bm + lr) * 2048 + lc;
  const float* Sp1 = Sb + (size_t)(bm + 64 + lr) * 2048 + lc;
  const float* Vp0 = Vb + (size_t)vr * CDIM + bc + vc;
  const float* Vp1 = Vb + (size_t)(8 + vr) * CDIM + bc + vc;
  float acc[8][8] = {};
  float4 a0 = *(const float4*)(Sp0);
  float4 a1 = *(const float4*)(Sp1);
  float4 b0 = *(const float4*)(Vp0);
  float4 b1 = *(const float4*)(Vp1);
  for (int k0 = 0; k0 < 2048; k0 += 16) {
    __syncthreads();
    As[lc + 0][lr] = a0.x; As[lc + 1][lr] = a0.y;
    As[lc + 2][lr] = a0.z; As[lc + 3][lr] = a0.w;
    As[lc + 0][64 + lr] = a1.x; As[lc + 1][64 + lr] = a1.y;
    As[lc + 2][64 + lr] = a1.z; As[lc + 3][64 + lr] = a1.w;
    *(float4*)&Bs[vr][vc] = b0;
    *(float4*)&Bs[8 + vr][vc] = b1;
    __syncthreads();
    if (k0 + 16 < 2048) {
      a0 = *(const float4*)(Sp0 + k0 + 16);
      a1 = *(const float4*)(Sp1 + k0 + 16);
      b0 = *(const float4*)(Vp0 + (size_t)(k0 + 16) * CDIM);
      b1 = *(const float4*)(Vp1 + (size_t)(k0 + 16) * CDIM);
    }
#pragma unroll
    for (int k = 0; k < 16; ++k) {
      const float4 x0 = *(const float4*)&As[k][ty << 2];
      const float4 x1 = *(const float4*)&As[k][64 + (ty << 2)];
      const float4 y0 = *(const float4*)&Bs[k][tx << 2];
      const float4 y1 = *(const float4*)&Bs[k][64 + (tx << 2)];
      const float ar[8] = {x0.x, x0.y, x0.z, x0.w, x1.x, x1.y, x1.z, x1.w};
      const float br[8] = {y0.x, y0.y, y0.z, y0.w, y1.x, y1.y, y1.z, y1.w};
#pragma unroll
      for (int i = 0; i < 8; ++i)
#pragma unroll
        for (int j = 0; j < 8; ++j) acc[i][j] = fmaf(ar[i], br[j], acc[i][j]);
    }
  }
#pragma unroll
  for (int i = 0; i < 8; ++i) {
    const int m = bm + ((i < 4) ? ((ty << 2) + i) : (64 + (ty << 2) + i - 4));
    float* op0 = Ob + (size_t)m * CDIM + bc + (tx << 2);
    float* op1 = Ob + (size_t)m * CDIM + bc + 64 + (tx << 2);
    float4 o0, o1;
    o0.x = acc[i][0]; o0.y = acc[i][1]; o0.z = acc[i][2]; o0.w = acc[i][3];
    o1.x = acc[i][4]; o1.y = acc[i][5]; o1.z = acc[i][6]; o1.w = acc[i][7];
    *(float4*)op0 = o0;
    *(float4*)op1 = o1;
  }
}

// ---------------- launch ----------------
extern "C" void kernel_launch(void* const* d_in, const int* in_sizes, int n_in,
                              void* d_out, int out_size, void* d_ws,
                              size_t ws_size, hipStream_t stream) {
  const float* query   = (const float*)d_in[0];
  const float* context = (const float*)d_in[1];
  const float* eps     = (const float*)d_in[2];
  const float* Wq      = (const float*)d_in[3];
  const float* bq      = (const float*)d_in[4];
  const float* Wk      = (const float*)d_in[5];
  const float* bk      = (const float*)d_in[6];
  const float* Wv      = (const float*)d_in[7];
  const float* bv      = (const float*)d_in[8];
  const float* Wo      = (const float*)d_in[9];
  const float* bo      = (const float*)d_in[10];
  const float* ln_k_g  = (const float*)d_in[11];
  const float* ln_k_b  = (const float*)d_in[12];
  const float* ln_v_g  = (const float*)d_in[13];
  const float* ln_v_b  = (const float*)d_in[14];
  const float* gate    = (const float*)d_in[15];

  // ---- workspace map, NEED = 192,937,984 B (184 MiB). Liveness:
  //  @0          varC fp32 50.3M [steps 1..4]; S1 fp32 67.1M [6a..8] aliases
  //              (varC dead@4; bytes 50.3M..67.1M untouched before 6a)
  //  @67108864   muB fp32 50.3M  [1..8]  (K mu -> V mu -> Vs in place)
  //  @117440512  kmuF fp16 25.2M [2..6a]
  //  @142606336  kvarF fp16 25.2M [2..6b]
  //  @167772160  qF 12.6M [5..6a] ; @180355072 q2F 12.6M [5..6b]
  //              Obuf fp32 25.2M [8..9] aliases qF+q2F (dead after 6b)
  const size_t NEED = 192937984ull;
  if (ws_size < NEED) return;  // fail safely (no OOB writes)
  char* wsb = (char*)d_ws;
  float*    varC = (float*)(wsb);
  float*    S1   = (float*)(wsb);                  // alias, from 6a
  float*    muB  = (float*)(wsb + 67108864);
  _Float16* kmuF = (_Float16*)(wsb + 117440512);
  _Float16* kvarF= (_Float16*)(wsb + 142606336);
  _Float16* qF   = (_Float16*)(wsb + 167772160);
  _Float16* q2F  = (_Float16*)(wsb + 180355072);
  float*    Obuf = (float*)(wsb + 167772160);      // alias qF/q2F, from 8

  const dim3 blk(256);
  // 1. K proj (fp32 in, cvt in staging): mu -> muB, softplus(lv)+1e-6 -> varC
  hgemm_nt<0, 6><<<dim3(12, 128, 1), blk, 0, stream>>>(
      context, Wk, bk, muB, varC, 16384, 1536, 768, 0, 0, 0,
      nullptr, nullptr, nullptr, nullptr);
  // 2. K post: LN -> kmuF fp16, var -> kvarF fp16
  ln_post_k<<<dim3(16384), blk, 0, stream>>>(muB, varC, ln_k_g, ln_k_b, kmuF,
                                             kvarF);
  // 3. V proj (reuses muB/varC)
  hgemm_nt<0, 6><<<dim3(12, 128, 1), blk, 0, stream>>>(
      context, Wv, bv, muB, varC, 16384, 1536, 768, 0, 0, 0,
      nullptr, nullptr, nullptr, nullptr);
  // 4. V post: Vs = LN(mu) + sqrt(var)*eps, in-place in muB
  ln_post_v<<<dim3(16384), blk, 0, stream>>>(muB, varC, ln_v_g, ln_v_b, eps);
  // 5. Q proj: qF = fp16(Q), q2F = fp16(Q^2)
  hgemm_nt<0, 1><<<dim3(6, 64, 1), blk, 0, stream>>>(
      query, Wq, bq, nullptr, nullptr, 8192, 768, 768, 0, 0, 0,
      qF, q2F, nullptr, nullptr);
  // 6a. S1 = Q @ Kmu^T (batched z=8, fp16 direct)
  hgemm_nt<1, 2><<<dim3(16, 8, 8), blk, 0, stream>>>(
      qF, kmuF, nullptr, S1, nullptr, 1024, 2048, 768, 786432, 1572864,
      2097152, nullptr, nullptr, nullptr, nullptr);
  // 6b. S1 = S1/sqrt(C) - 2.35*sqrt((Q^2 @ Kvar^T)/C)  (in-place combine)
  hgemm_nt<1, 3><<<dim3(16, 8, 8), blk, 0, stream>>>(
      q2F, kvarF, nullptr, S1, nullptr, 1024, 2048, 768, 786432, 1572864,
      2097152, nullptr, nullptr, nullptr, nullptr);
  // 7. softmax rows, in place -> attn
  softmax_rows<<<dim3(8192), blk, 0, stream>>>(S1);
  // 8. O = attn @ Vs (fp32 vector GEMM)
  gemm_nn_av<<<dim3(6, 8, 8), blk, 0, stream>>>(S1, muB, Obuf);
  // 9. final: d_out = g*(O @ Wo^T + bo) + (1-g)*query  (cvt in staging)
  hgemm_nt<0, 5><<<dim3(6, 64, 1), blk, 0, stream>>>(
      Obuf, Wo, bo, (float*)d_out, nullptr, 8192, 768, 768, 0, 0, 0,
      nullptr, nullptr, query, gate);
}